// Round 15
// baseline (2123.032 us; speedup 1.0000x reference)
//
#include <hip/hip_runtime.h>
#include <hip/hip_bf16.h>

// RNN_80848464380442: B=64, S=2048, V=50257, E=128, H=256, C=2 (f32 in/out, x int32)
// Stage 1: xw[tok][sig(j)] = bU[j] + sum_e emb[x]*W  (fp16 to ws, sigma-permuted cols)
// Stage 2: MFMA scan, 4 blocks x 16 rows = TWO independent 8-row streams per block,
//          software-pipelined between barriers (P-reads,P-MFMA,Q-reads,Q-MFMA,
//          P-epi,Q-epi,barrier): two dep chains interleave, stalls filled.
//          8 waves x 2 N-tiles; D rows 8-15 duplicate 0-7 -> split epilogue (R14);
//          xw folded into MFMA C; 2-step prefetch ring; plain __syncthreads.
// Stage 3: logits + h output post-loop from LDS.
// sigma: j = 32w+16s+n  ->  p = 32w+2n+s

#define HB 256
#define EB 128
#define SB 2048
#define BB 64
#define TPB 32
#define ROWS 8
#define PITCH 264   // u16/row = 528 B

typedef unsigned short u16;
typedef __attribute__((ext_vector_type(4))) float f32x4;
typedef __attribute__((ext_vector_type(8))) _Float16 f16x8;
typedef __attribute__((ext_vector_type(2))) __fp16 fp16x2_t;

__device__ __forceinline__ u16 f2h_bits(float f) {
    union { _Float16 h; u16 b; } x; x.h = (_Float16)f; return x.b;
}
__device__ __forceinline__ float h2f_bits(u16 b) {
    union { u16 b; _Float16 h; } x; x.b = b; return (float)x.h;
}
__device__ __forceinline__ float tanh_fast(float z) {
    float E = exp2f(z * 2.885390082f);             // e^(2z); tanh = 1 - 2/(e^2z + 1)
    return fmaf(-2.f, __builtin_amdgcn_rcpf(E + 1.f), 1.f);
}
__device__ __forceinline__ unsigned pkrtz(float a, float b) {
    fp16x2_t p = __builtin_amdgcn_cvt_pkrtz(a, b);
    return __builtin_bit_cast(unsigned, p);
}

__device__ __forceinline__ int sig(int j)    { return (j & 0xE0) | ((j & 15) << 1) | ((j >> 4) & 1); }
__device__ __forceinline__ int invsig(int p) { return (p & 0xE0) | ((p & 1) << 4) | ((p >> 1) & 15); }

// ---------------- Stage 1: embed + project (32 tokens per 256-thread block) --------
__global__ __launch_bounds__(256) void embed_proj(
    const int* __restrict__ x, const float* __restrict__ emb,
    const float* __restrict__ W, const float* __restrict__ bU,
    u16* __restrict__ xw)
{
    __shared__ __align__(16) float el[TPB][EB];   // 16 KB
    __shared__ int toks[TPB];

    const int tid = threadIdx.x;
    const long base = (long)blockIdx.x * TPB;

    if (tid < TPB) toks[tid] = x[base + tid];
    __syncthreads();

    for (int r = 0; r < TPB * EB / 256; ++r) {
        int i = tid + r * 256;
        int row = i >> 7, e = i & (EB - 1);
        int u = toks[row];
        el[row][e] = (u == 0) ? 0.f : emb[(size_t)u * EB + e];   // padding_idx=0
    }
    __syncthreads();

    const int j = tid;
    const int sj = sig(j);
    const float bu = bU[j];
    float acc[TPB];
    #pragma unroll
    for (int t = 0; t < TPB; ++t) acc[t] = bu;

    for (int e0 = 0; e0 < EB; e0 += 4) {
        float w0 = W[(e0 + 0) * HB + j];
        float w1 = W[(e0 + 1) * HB + j];
        float w2 = W[(e0 + 2) * HB + j];
        float w3 = W[(e0 + 3) * HB + j];
        #pragma unroll
        for (int t = 0; t < TPB; ++t) {
            float4 ev = *(const float4*)&el[t][e0];
            acc[t] = fmaf(ev.x, w0, acc[t]);
            acc[t] = fmaf(ev.y, w1, acc[t]);
            acc[t] = fmaf(ev.z, w2, acc[t]);
            acc[t] = fmaf(ev.w, w3, acc[t]);
        }
    }
    #pragma unroll
    for (int t = 0; t < TPB; ++t)
        xw[(base + t) * HB + sj] = f2h_bits(acc[t]);
}

// ---------------- Stage 2+3: MFMA scan, 4 blocks x 512 threads, dual stream --------
// STEP2(T, ...): both streams' step T between one barrier pair.
#define STEP2(T, XP0, XP1, XQ0, XQ1)                                               \
  {                                                                                \
    const int cb = (T) & 1, nb = cb ^ 1;                                           \
    const unsigned toff = (unsigned)(((T) + 2 < SB) ? (T) + 2 : SB - 1) * HB;      \
    /* ---- stream P: C-init, prefetch, A-reads, MFMA ---- */                      \
    f32x4 aP0, aP1;                                                                \
    {                                                                              \
        float c00 = h2f_bits((u16)(XP0 & 0xffffu));                                \
        float c01 = h2f_bits((u16)(XP0 >> 16));                                    \
        float c10 = h2f_bits((u16)(XP1 & 0xffffu));                                \
        float c11 = h2f_bits((u16)(XP1 >> 16));                                    \
        aP0[0] = c00; aP0[2] = c00; aP0[1] = c10; aP0[3] = c10;                    \
        aP1[0] = c01; aP1[2] = c01; aP1[1] = c11; aP1[3] = c11;                    \
    }                                                                              \
    XP0 = *(const unsigned*)&xw[gP0 + toff];                                       \
    XP1 = *(const unsigned*)&xw[gP1 + toff];                                       \
    f16x8 AfP[8];                                                                  \
    _Pragma("unroll")                                                              \
    for (int ks = 0; ks < 8; ++ks) {                                               \
        uint4 av = *(const uint4*)&HP[cb][n & 7][ks * 32 + kg * 8];                \
        AfP[ks] = __builtin_bit_cast(f16x8, av);                                   \
    }                                                                              \
    _Pragma("unroll")                                                              \
    for (int ks = 0; ks < 8; ++ks) {                                               \
        aP0 = __builtin_amdgcn_mfma_f32_16x16x32_f16(AfP[ks], Bf[0][ks], aP0, 0, 0, 0); \
        aP1 = __builtin_amdgcn_mfma_f32_16x16x32_f16(AfP[ks], Bf[1][ks], aP1, 0, 0, 0); \
    }                                                                              \
    /* ---- stream Q: C-init, prefetch, A-reads, MFMA (fills P's latency) ---- */  \
    f32x4 aQ0, aQ1;                                                                \
    {                                                                              \
        float c00 = h2f_bits((u16)(XQ0 & 0xffffu));                                \
        float c01 = h2f_bits((u16)(XQ0 >> 16));                                    \
        float c10 = h2f_bits((u16)(XQ1 & 0xffffu));                                \
        float c11 = h2f_bits((u16)(XQ1 >> 16));                                    \
        aQ0[0] = c00; aQ0[2] = c00; aQ0[1] = c10; aQ0[3] = c10;                    \
        aQ1[0] = c01; aQ1[2] = c01; aQ1[1] = c11; aQ1[3] = c11;                    \
    }                                                                              \
    XQ0 = *(const unsigned*)&xw[gQ0 + toff];                                       \
    XQ1 = *(const unsigned*)&xw[gQ1 + toff];                                       \
    f16x8 AfQ[8];                                                                  \
    _Pragma("unroll")                                                              \
    for (int ks = 0; ks < 8; ++ks) {                                               \
        uint4 av = *(const uint4*)&HQ[cb][n & 7][ks * 32 + kg * 8];                \
        AfQ[ks] = __builtin_bit_cast(f16x8, av);                                   \
    }                                                                              \
    _Pragma("unroll")                                                              \
    for (int ks = 0; ks < 8; ++ks) {                                               \
        aQ0 = __builtin_amdgcn_mfma_f32_16x16x32_f16(AfQ[ks], Bf[0][ks], aQ0, 0, 0, 0); \
        aQ1 = __builtin_amdgcn_mfma_f32_16x16x32_f16(AfQ[ks], Bf[1][ks], aQ1, 0, 0, 0); \
    }                                                                              \
    /* ---- epilogue P (hidden under Q's MFMA latency), then Q ---- */             \
    {                                                                              \
        float s00 = hi ? aP0[2] : aP0[0];                                          \
        float s01 = hi ? aP0[3] : aP0[1];                                          \
        float s10 = hi ? aP1[2] : aP1[0];                                          \
        float s11 = hi ? aP1[3] : aP1[1];                                          \
        unsigned pkA = pkrtz(tanh_fast(s00), tanh_fast(s10));                      \
        unsigned pkB = pkrtz(tanh_fast(s01), tanh_fast(s11));                      \
        u16* wp = &HP[nb][0][0] + wbase;                                           \
        *(unsigned*)(wp)         = pkA;                                            \
        *(unsigned*)(wp + PITCH) = pkB;                                            \
    }                                                                              \
    {                                                                              \
        float s00 = hi ? aQ0[2] : aQ0[0];                                          \
        float s01 = hi ? aQ0[3] : aQ0[1];                                          \
        float s10 = hi ? aQ1[2] : aQ1[0];                                          \
        float s11 = hi ? aQ1[3] : aQ1[1];                                          \
        unsigned pkA = pkrtz(tanh_fast(s00), tanh_fast(s10));                      \
        unsigned pkB = pkrtz(tanh_fast(s01), tanh_fast(s11));                      \
        u16* wp = &HQ[nb][0][0] + wbase;                                           \
        *(unsigned*)(wp)         = pkA;                                            \
        *(unsigned*)(wp + PITCH) = pkB;                                            \
    }                                                                              \
    __syncthreads();                                                               \
  }

__global__ __launch_bounds__(512, 2) void rnn_scan_mfma(
    const u16* __restrict__ xw, const float* __restrict__ U,
    const float* __restrict__ V, const float* __restrict__ bV,
    float* __restrict__ out)
{
    __shared__ __align__(16) u16 HP[2][ROWS][PITCH];  // stream P h, double-buffered
    __shared__ __align__(16) u16 HQ[2][ROWS][PITCH];  // stream Q h, double-buffered

    const int tid  = threadIdx.x;
    const int lane = tid & 63;
    const int w    = tid >> 6;            // wave 0..7, owns N-tiles 2w, 2w+1
    const int b0   = blockIdx.x * 16;     // rows b0..b0+7 = P, b0+8..b0+15 = Q

    {   // zero all H buffers (incl. pad)
        unsigned* hz = (unsigned*)&HP[0][0][0];
        for (int i = tid; i < 2 * ROWS * PITCH / 2; i += 512) hz[i] = 0u;
        unsigned* hz2 = (unsigned*)&HQ[0][0][0];
        for (int i = tid; i < 2 * ROWS * PITCH / 2; i += 512) hz2[i] = 0u;
    }

    const int n  = lane & 15;             // A-m / B-n / D-col
    const int kg = lane >> 4;             // 0..3
    const bool hi = kg >= 2;

    // ---- B-frag preload via sigma^-1: Bf[s][ks], tile nt=2w+s, col j_out=nt*16+n ----
    f16x8 Bf[2][8];
    #pragma unroll
    for (int s = 0; s < 2; ++s) {
        const int col = (2 * w + s) * 16 + n;
        #pragma unroll
        for (int ks = 0; ks < 8; ++ks) {
            union { f16x8 v; u16 h[8]; } tmp;
            #pragma unroll
            for (int e = 0; e < 8; ++e) {
                const int p = ks * 32 + kg * 8 + e;          // storage k
                const int jin = invsig(p);                   // actual contraction j
                tmp.h[e] = f2h_bits(U[(size_t)jin * HB + col]);
            }
            Bf[s][ks] = tmp.v;
        }
    }

    // ---- per-lane mapping: owns rows rb, rb+1 at col pair pbase = 32w+2n ----
    const int pbase = 32 * w + 2 * n;
    const int rb = (kg & 1) * 4 + (hi ? 2 : 0);   // rows {0,1},{2,3},{4,5},{6,7}
    const int wbase = rb * PITCH + pbase;
    const unsigned gP0 = ((unsigned)(b0 + rb) * SB) * HB + pbase;
    const unsigned gP1 = gP0 + SB * HB;
    const unsigned gQ0 = gP0 + 8u * SB * HB;
    const unsigned gQ1 = gQ0 + SB * HB;
    unsigned XPA0 = *(const unsigned*)&xw[gP0];            // t = 0
    unsigned XPA1 = *(const unsigned*)&xw[gP1];
    unsigned XQA0 = *(const unsigned*)&xw[gQ0];
    unsigned XQA1 = *(const unsigned*)&xw[gQ1];
    unsigned XPB0 = *(const unsigned*)&xw[gP0 + HB];       // t = 1
    unsigned XPB1 = *(const unsigned*)&xw[gP1 + HB];
    unsigned XQB0 = *(const unsigned*)&xw[gQ0 + HB];
    unsigned XQB1 = *(const unsigned*)&xw[gQ1 + HB];
    __syncthreads();

    for (int t = 0; t < SB; t += 2) {
        STEP2(t,     XPA0, XPA1, XQA0, XQA1);
        STEP2(t + 1, XPB0, XPB1, XQB0, XQB1);
    }

    // h output (f32 from fp16 buf 0; SB even -> final h in buffer 0)
    for (int i = tid; i < 16 * HB; i += 512) {
        const int r = i >> 8, p = i & 255;
        const u16 hv = (r < 8) ? HP[0][r][p] : HQ[0][r - 8][p];
        out[BB * 2 + (size_t)(b0 + r) * HB + invsig(p)] = h2f_bits(hv);
    }

    // logits: first 256 threads = 16 rows x 16 partials
    if (tid < 16 * 16) {
        const int r = tid >> 4, part = tid & 15;
        float s0 = 0.f, s1 = 0.f;
        #pragma unroll
        for (int i = 0; i < 16; ++i) {
            const int p = part * 16 + i;
            const int j = invsig(p);
            const u16 hv = (r < 8) ? HP[0][r][p] : HQ[0][r - 8][p];
            float hh = h2f_bits(hv);
            s0 = fmaf(hh, V[j * 2 + 0], s0);
            s1 = fmaf(hh, V[j * 2 + 1], s1);
        }
        #pragma unroll
        for (int o = 8; o > 0; o >>= 1) {
            s0 += __shfl_down(s0, o, 16);
            s1 += __shfl_down(s1, o, 16);
        }
        if (part == 0) {
            out[(size_t)(b0 + r) * 2 + 0] = s0 + bV[0];
            out[(size_t)(b0 + r) * 2 + 1] = s1 + bV[1];
        }
    }
}

extern "C" void kernel_launch(void* const* d_in, const int* in_sizes, int n_in,
                              void* d_out, int out_size, void* d_ws, size_t ws_size,
                              hipStream_t stream) {
    const int*   x   = (const int*)d_in[0];
    const float* emb = (const float*)d_in[1];
    const float* W   = (const float*)d_in[2];
    const float* U   = (const float*)d_in[3];
    const float* bU  = (const float*)d_in[4];
    const float* V   = (const float*)d_in[5];
    const float* bV  = (const float*)d_in[6];
    float* out = (float*)d_out;
    u16*   xw  = (u16*)d_ws;   // 64 MiB fp16 scratch, sigma-permuted columns

    embed_proj<<<BB * SB / TPB, 256, 0, stream>>>(x, emb, W, bU, xw);
    rnn_scan_mfma<<<BB / 16, 512, 0, stream>>>(xw, U, V, bV, out);
}

// Round 16
// 1281.029 us; speedup vs baseline: 1.6573x; 1.6573x over previous
//
#include <hip/hip_runtime.h>
#include <hip/hip_bf16.h>

// RNN_80848464380442: B=64, S=2048, V=50257, E=128, H=256, C=2 (f32 in/out, x int32)
// Stage 1: xw[tok][sig(j)] = bU[j] + sum_e emb[x]*W  (fp16 to ws, sigma-permuted cols)
// Stage 2: MFMA scan, 16 blocks x 4 batch rows, 4 waves x 4 N-tiles (256 thr).
//          LDS-issue-bound fix (R15 lesson: time ~ ds_read count): per CU only
//          4 waves x 8 b128 A-reads/step. Rows tiled 4x in M=16 (broadcast row n&3,
//          same-addr = free); D slot q == batch row q -> lane owns row kg:
//          4 tanh + 1 b64 write. xw folded into MFMA C (1 uint2/lane).
//          2-step prefetch ring; plain __syncthreads.
// Stage 3: logits + h output post-loop from LDS.
// sigma: j = 64w+16s+n  ->  p = 64w+4n+s   (lane's 4 tile-values contiguous)

#define HB 256
#define EB 128
#define SB 2048
#define BB 64
#define TPB 32
#define ROWS 4
#define PITCH 272   // u16/row = 544 B; row bank-start 8r, kg offset 4kg -> <=2-way (free)

typedef unsigned short u16;
typedef __attribute__((ext_vector_type(4))) float f32x4;
typedef __attribute__((ext_vector_type(8))) _Float16 f16x8;
typedef __attribute__((ext_vector_type(2))) __fp16 fp16x2_t;

__device__ __forceinline__ u16 f2h_bits(float f) {
    union { _Float16 h; u16 b; } x; x.h = (_Float16)f; return x.b;
}
__device__ __forceinline__ float h2f_bits(u16 b) {
    union { u16 b; _Float16 h; } x; x.b = b; return (float)x.h;
}
__device__ __forceinline__ float tanh_fast(float z) {
    float E = exp2f(z * 2.885390082f);             // e^(2z); tanh = 1 - 2/(e^2z + 1)
    return fmaf(-2.f, __builtin_amdgcn_rcpf(E + 1.f), 1.f);
}
__device__ __forceinline__ unsigned pkrtz(float a, float b) {
    fp16x2_t p = __builtin_amdgcn_cvt_pkrtz(a, b);
    return __builtin_bit_cast(unsigned, p);
}
__device__ __forceinline__ float sel4(f32x4 v, int kg) {   // v[kg] via cndmask chain
    float r = v[0];
    r = (kg == 1) ? v[1] : r;
    r = (kg == 2) ? v[2] : r;
    r = (kg == 3) ? v[3] : r;
    return r;
}

__device__ __forceinline__ int sig(int j)    { return (j & 0xC0) | ((j & 15) << 2) | ((j >> 4) & 3); }
__device__ __forceinline__ int invsig(int p) { return (p & 0xC0) | ((p & 3) << 4) | ((p >> 2) & 15); }

// ---------------- Stage 1: embed + project (32 tokens per 256-thread block) --------
__global__ __launch_bounds__(256) void embed_proj(
    const int* __restrict__ x, const float* __restrict__ emb,
    const float* __restrict__ W, const float* __restrict__ bU,
    u16* __restrict__ xw)
{
    __shared__ __align__(16) float el[TPB][EB];   // 16 KB
    __shared__ int toks[TPB];

    const int tid = threadIdx.x;
    const long base = (long)blockIdx.x * TPB;

    if (tid < TPB) toks[tid] = x[base + tid];
    __syncthreads();

    for (int r = 0; r < TPB * EB / 256; ++r) {
        int i = tid + r * 256;
        int row = i >> 7, e = i & (EB - 1);
        int u = toks[row];
        el[row][e] = (u == 0) ? 0.f : emb[(size_t)u * EB + e];   // padding_idx=0
    }
    __syncthreads();

    const int j = tid;
    const int sj = sig(j);
    const float bu = bU[j];
    float acc[TPB];
    #pragma unroll
    for (int t = 0; t < TPB; ++t) acc[t] = bu;

    for (int e0 = 0; e0 < EB; e0 += 4) {
        float w0 = W[(e0 + 0) * HB + j];
        float w1 = W[(e0 + 1) * HB + j];
        float w2 = W[(e0 + 2) * HB + j];
        float w3 = W[(e0 + 3) * HB + j];
        #pragma unroll
        for (int t = 0; t < TPB; ++t) {
            float4 ev = *(const float4*)&el[t][e0];
            acc[t] = fmaf(ev.x, w0, acc[t]);
            acc[t] = fmaf(ev.y, w1, acc[t]);
            acc[t] = fmaf(ev.z, w2, acc[t]);
            acc[t] = fmaf(ev.w, w3, acc[t]);
        }
    }
    #pragma unroll
    for (int t = 0; t < TPB; ++t)
        xw[(base + t) * HB + sj] = f2h_bits(acc[t]);
}

// ---------------- Stage 2+3: MFMA scan, 16 blocks x 256 threads (4 waves) ----------
// STEP(T, X): X (uint2) holds step T's 4 xw values for lane's row kg (tiles s=0..3).
// C-init splats xv[s] into acc_s (only slot kg is kept), reissue X <- T+2,
// broadcast A-reads (row n&3), 32 MFMAs (4 chains), 4 tanh, one b64 write, barrier.
#define STEP(T, X)                                                                 \
  {                                                                                \
    const int cb = (T) & 1, nb = cb ^ 1;                                           \
    float xv0 = h2f_bits((u16)(X.x & 0xffffu));                                    \
    float xv1 = h2f_bits((u16)(X.x >> 16));                                        \
    float xv2 = h2f_bits((u16)(X.y & 0xffffu));                                    \
    float xv3 = h2f_bits((u16)(X.y >> 16));                                        \
    f32x4 accA = {xv0, xv0, xv0, xv0};                                             \
    f32x4 accB = {xv1, xv1, xv1, xv1};                                             \
    f32x4 accC = {xv2, xv2, xv2, xv2};                                             \
    f32x4 accD = {xv3, xv3, xv3, xv3};                                             \
    {                                                                              \
        const unsigned toff = (unsigned)(((T) + 2 < SB) ? (T) + 2 : SB - 1) * HB;  \
        X = *(const uint2*)&xw[gb + toff];                                         \
    }                                                                              \
    f16x8 Af[8];                                                                   \
    _Pragma("unroll")                                                              \
    for (int ks = 0; ks < 8; ++ks) {                                               \
        uint4 av = *(const uint4*)&H[cb][n & 3][ks * 32 + kg * 8];                 \
        Af[ks] = __builtin_bit_cast(f16x8, av);                                    \
    }                                                                              \
    _Pragma("unroll")                                                              \
    for (int ks = 0; ks < 8; ++ks) {                                               \
        accA = __builtin_amdgcn_mfma_f32_16x16x32_f16(Af[ks], Bf[0][ks], accA, 0, 0, 0); \
        accB = __builtin_amdgcn_mfma_f32_16x16x32_f16(Af[ks], Bf[1][ks], accB, 0, 0, 0); \
        accC = __builtin_amdgcn_mfma_f32_16x16x32_f16(Af[ks], Bf[2][ks], accC, 0, 0, 0); \
        accD = __builtin_amdgcn_mfma_f32_16x16x32_f16(Af[ks], Bf[3][ks], accD, 0, 0, 0); \
    }                                                                              \
    {                                                                              \
        float t0 = tanh_fast(sel4(accA, kg));                                      \
        float t1 = tanh_fast(sel4(accB, kg));                                      \
        float t2 = tanh_fast(sel4(accC, kg));                                      \
        float t3 = tanh_fast(sel4(accD, kg));                                      \
        *(uint2*)&H[nb][kg][pbase] = make_uint2(pkrtz(t0, t1), pkrtz(t2, t3));     \
    }                                                                              \
    __syncthreads();                                                               \
  }

__global__ __launch_bounds__(256, 1) void rnn_scan_mfma(
    const u16* __restrict__ xw, const float* __restrict__ U,
    const float* __restrict__ V, const float* __restrict__ bV,
    float* __restrict__ out)
{
    __shared__ __align__(16) u16 H[2][ROWS][PITCH];   // double-buffered h (fp16), sigma order

    const int tid  = threadIdx.x;
    const int lane = tid & 63;
    const int w    = tid >> 6;            // wave 0..3, owns N-tiles 4w..4w+3
    const int b0   = blockIdx.x * ROWS;

    {   // zero both H buffers (incl. pad)
        unsigned* hz = (unsigned*)H;
        for (int i = tid; i < 2 * ROWS * PITCH / 2; i += 256) hz[i] = 0u;
    }

    const int n  = lane & 15;             // A-m / B-n / D-col
    const int kg = lane >> 4;             // 0..3; lane owns batch row kg

    // ---- B-frag preload via sigma^-1: Bf[s][ks], tile nt=4w+s, col j_out=nt*16+n ----
    f16x8 Bf[4][8];
    #pragma unroll
    for (int s = 0; s < 4; ++s) {
        const int col = (4 * w + s) * 16 + n;
        #pragma unroll
        for (int ks = 0; ks < 8; ++ks) {
            union { f16x8 v; u16 h[8]; } tmp;
            #pragma unroll
            for (int e = 0; e < 8; ++e) {
                const int p = ks * 32 + kg * 8 + e;          // storage k
                const int jin = invsig(p);                   // actual contraction j
                tmp.h[e] = f2h_bits(U[(size_t)jin * HB + col]);
            }
            Bf[s][ks] = tmp.v;
        }
    }

    // ---- per-lane mapping: row kg, sigma col base pbase = 64w+4n (tiles s=0..3) ----
    const int pbase = 64 * w + 4 * n;
    const unsigned gb = ((unsigned)(b0 + kg) * SB) * HB + pbase;
    uint2 XA = *(const uint2*)&xw[gb];                   // t = 0
    uint2 XB = *(const uint2*)&xw[gb + HB];              // t = 1
    __syncthreads();

    for (int t = 0; t < SB; t += 2) {
        STEP(t,     XA);
        STEP(t + 1, XB);
    }

    // h output (f32 from fp16 H[0]; SB even -> final h in buffer 0)
    for (int i = tid; i < ROWS * HB; i += 256) {
        const int r = i >> 8, p = i & 255;
        out[BB * 2 + (size_t)(b0 + r) * HB + invsig(p)] = h2f_bits(H[0][r][p]);
    }

    // logits: first 64 threads = 4 rows x 16 partials
    if (tid < ROWS * 16) {
        const int r = tid >> 4, part = tid & 15;
        float s0 = 0.f, s1 = 0.f;
        #pragma unroll
        for (int i = 0; i < 16; ++i) {
            const int p = part * 16 + i;
            const int j = invsig(p);
            float hh = h2f_bits(H[0][r][p]);
            s0 = fmaf(hh, V[j * 2 + 0], s0);
            s1 = fmaf(hh, V[j * 2 + 1], s1);
        }
        #pragma unroll
        for (int o = 8; o > 0; o >>= 1) {
            s0 += __shfl_down(s0, o, 16);
            s1 += __shfl_down(s1, o, 16);
        }
        if (part == 0) {
            out[(size_t)(b0 + r) * 2 + 0] = s0 + bV[0];
            out[(size_t)(b0 + r) * 2 + 1] = s1 + bV[1];
        }
    }
}

extern "C" void kernel_launch(void* const* d_in, const int* in_sizes, int n_in,
                              void* d_out, int out_size, void* d_ws, size_t ws_size,
                              hipStream_t stream) {
    const int*   x   = (const int*)d_in[0];
    const float* emb = (const float*)d_in[1];
    const float* W   = (const float*)d_in[2];
    const float* U   = (const float*)d_in[3];
    const float* bU  = (const float*)d_in[4];
    const float* V   = (const float*)d_in[5];
    const float* bV  = (const float*)d_in[6];
    float* out = (float*)d_out;
    u16*   xw  = (u16*)d_ws;   // 64 MiB fp16 scratch, sigma-permuted columns

    embed_proj<<<BB * SB / TPB, 256, 0, stream>>>(x, emb, W, bU, xw);
    rnn_scan_mfma<<<BB / ROWS, 256, 0, stream>>>(xw, U, V, bV, out);
}